// Round 6
// baseline (1442.049 us; speedup 1.0000x reference)
//
#include <hip/hip_runtime.h>

#define A_N   50000
#define P_N   100000
#define DIN   128
#define H_DIM 256
#define C_CLS 40
#define E_N   300000
#define EPS_LN 1e-5f

typedef short bf16x8 __attribute__((ext_vector_type(8)));
typedef float f32x4  __attribute__((ext_vector_type(4)));
typedef unsigned short u16;

__device__ __forceinline__ u16 f2bf(float x) {
    union { float f; unsigned u; } v; v.f = x;
    unsigned r = v.u + 0x7fff + ((v.u >> 16) & 1);
    return (u16)(r >> 16);
}
__device__ __forceinline__ float bf2f(u16 h) {
    union { unsigned u; float f; } v; v.u = ((unsigned)h) << 16;
    return v.f;
}

// async global->LDS, 16 B per lane; lds base must be wave-uniform (HW scatters lane*16)
__device__ __forceinline__ void gl2lds16(const u16* g, u16* ldsbase) {
    __builtin_amdgcn_global_load_lds(
        (const __attribute__((address_space(1))) unsigned int*)g,
        (__attribute__((address_space(3))) unsigned int*)ldsbase, 16, 0, 0);
}

// Swizzle (64-B LDS rows, 4 x 16-B chunks): LDS[row][c] = G[row][c ^ ((row>>1)&3)].
// Applied on the global SOURCE of gl2lds (LDS linear, m104/m173) and on the ds_read chunk.
// Read bank algebra: lane(quad,lm) -> bank 16*(lm&1) + 4*(quad^((lm>>1)&3)): 2 lanes per
// bank-group = 2-way = free (m136).  Staging rows are lr+rg (lr mult of 16) -> f=(rg>>1)&3;
// read rows are base+lm (base mult of 16) -> f=(lm>>1)&3.

// ================= general bf16 MFMA GEMM: C[N,M] = sum_seg A_seg[N,K] @ (BT_seg[M,K])^T ======
// v2: counted-vmcnt double-buffer (v5-proven transform) + chunk swizzle.
// 128x128 tile, BK=32, 256 threads (4 waves), wave = 64x64 via 4x4 of 16x16x32 MFMA.
#define GBN 128
#define GBM 128

__launch_bounds__(256)
__global__ void gemm_mfma2(const u16* __restrict__ A0, const u16* __restrict__ A1,
                           const u16* __restrict__ A2,
                           const u16* __restrict__ B0, const u16* __restrict__ B1,
                           const u16* __restrict__ B2,
                           int nseg, const float* __restrict__ bias,
                           float* __restrict__ C32, u16* __restrict__ C16,
                           int N, int K, int M, int relu)
{
    __shared__ u16 As[2][GBN * 32];   // 2 x 8 KB
    __shared__ u16 Bs[2][GBM * 32];   // 2 x 8 KB

    const int tid  = threadIdx.x;
    const int wave = tid >> 6;
    const int lane = tid & 63;
    const int n0 = blockIdx.y * GBN;
    const int m0 = blockIdx.x * GBM;
    const int wrow = (wave >> 1) * 64;
    const int wcol = (wave & 1) * 64;
    const int lm   = lane & 15;
    const int quad = lane >> 4;
    const int rg = lane >> 2;      // staging: 4 lanes/row (64 B rows), 16 rows/instr
    const int ch = lane & 3;       // 16B chunk within row
    const int csrc = ((ch ^ ((rg >> 1) & 3)) << 3);   // swizzled source chunk (u16 units)
    const int xo   = ((quad ^ ((lm >> 1) & 3)) << 3); // swizzled read chunk (u16 units)

    f32x4 acc[4][4];
    #pragma unroll
    for (int i = 0; i < 4; ++i)
        #pragma unroll
        for (int j = 0; j < 4; ++j)
            acc[i][j] = (f32x4)0.0f;

    const int ks = K >> 5;         // K-steps per segment
    const int T  = nseg * ks;

    auto stage = [&](int t, int b) {
        int seg = 0, tt = t;
        while (tt >= ks) { tt -= ks; ++seg; }   // nseg <= 3
        const int k0 = tt * 32;
        const u16* Aseg = (seg == 0) ? A0 : (seg == 1) ? A1 : A2;
        const u16* Bseg = (seg == 0) ? B0 : (seg == 1) ? B1 : B2;
        #pragma unroll
        for (int i = 0; i < 2; ++i) {
            int lr = wave * 32 + i * 16;
            int grow = n0 + lr + rg; if (grow > N - 1) grow = N - 1;
            gl2lds16(Aseg + (size_t)grow * K + k0 + csrc, &As[b][lr * 32]);
        }
        #pragma unroll
        for (int i = 0; i < 2; ++i) {
            int lr = wave * 32 + i * 16;
            int brow = m0 + lr + rg; if (brow > M - 1) brow = M - 1;
            gl2lds16(Bseg + (size_t)brow * K + k0 + csrc, &Bs[b][lr * 32]);
        }
    };

    stage(0, 0);
    for (int t = 0; t < T; ++t) {
        if (t + 1 < T) {
            stage(t + 1, (t + 1) & 1);
            asm volatile("s_waitcnt vmcnt(4)" ::: "memory");  // tile t landed; t+1 in flight
        } else {
            asm volatile("s_waitcnt vmcnt(0)" ::: "memory");
        }
        __builtin_amdgcn_s_barrier();
        __builtin_amdgcn_sched_barrier(0);

        const u16* ap = &As[t & 1][0];
        const u16* bp = &Bs[t & 1][0];
        bf16x8 af[4], bfr[4];
        #pragma unroll
        for (int i = 0; i < 4; ++i)
            af[i] = *(const bf16x8*)&ap[(wrow + i * 16 + lm) * 32 + xo];
        #pragma unroll
        for (int j = 0; j < 4; ++j)
            bfr[j] = *(const bf16x8*)&bp[(wcol + j * 16 + lm) * 32 + xo];
        #pragma unroll
        for (int i = 0; i < 4; ++i)
            #pragma unroll
            for (int j = 0; j < 4; ++j)
                acc[i][j] = __builtin_amdgcn_mfma_f32_16x16x32_bf16(af[i], bfr[j], acc[i][j], 0, 0, 0);

        __builtin_amdgcn_sched_barrier(0);
        __builtin_amdgcn_s_barrier();
        __builtin_amdgcn_sched_barrier(0);
    }

    // epilogue: C/D layout col=lane&15, row=quad*4+reg
    float bj[4];
    #pragma unroll
    for (int j = 0; j < 4; ++j) {
        int gcol = m0 + wcol + j * 16 + lm;
        bj[j] = (bias && gcol < M) ? bias[gcol] : 0.f;
    }
    #pragma unroll
    for (int i = 0; i < 4; ++i) {
        #pragma unroll
        for (int r = 0; r < 4; ++r) {
            int grow = n0 + wrow + i * 16 + quad * 4 + r;
            if (grow >= N) continue;
            #pragma unroll
            for (int j = 0; j < 4; ++j) {
                int gcol = m0 + wcol + j * 16 + lm;
                if (gcol >= M) continue;
                float v = acc[i][j][r] + bj[j];
                if (relu) v = fmaxf(v, 0.f);
                if (C32) C32[(size_t)grow * M + gcol] = v;
                if (C16) C16[(size_t)grow * M + gcol] = f2bf(v);
            }
        }
    }
}

// ========== fused layer GEMM + relu + residual + LayerNorm, in-place on H (bf16) ==========
// v6 = v4 geometry x v5 sync x exact swizzle:
//   - wave = 64x64 tile (acc[4][4], 64 VGPR): 8 ds_read_b128 / 16 MFMA (block reads
//     1632 -> 768 vs v1/v5) -- the LDS-pipe term that capped v5 at 103 us.
//   - v5's counted-vmcnt dbuf: stage(t+1) -> vmcnt(5) -> s_barrier -> compute -> s_barrier.
//   - chunk swizzle (header comment) -> 2-way banks = free (v4's 8-way was 4.8e6 conflicts).
//   - LN = cross-wave reduction (v4), lnred aliased onto dead As space after the k-loop
//     (LDS stays 40 KB -> 4 blocks/CU, v5's occupancy).
// Safe in-place: block touches only its own 64 H rows; pass-1 reads precede the barrier,
// pass-2 writes follow it, same block.
__launch_bounds__(256)
__global__ void gemm_ln(const u16* __restrict__ A0, const u16* __restrict__ A1,
                        const u16* __restrict__ A2,
                        const u16* __restrict__ B0, const u16* __restrict__ B1,
                        const u16* __restrict__ B2,
                        int nseg, const float* __restrict__ bias,
                        const float* __restrict__ lng, const float* __restrict__ lnb,
                        u16* __restrict__ H, int N)
{
    __shared__ u16 As[2][64 * 32];    // 2 x 4 KB
    __shared__ u16 Bs[2][256 * 32];   // 2 x 16 KB

    const int tid  = threadIdx.x;
    const int wave = tid >> 6;
    const int lane = tid & 63;
    const int n0 = blockIdx.x * 64;
    const int lm   = lane & 15;
    const int quad = lane >> 4;
    const int rg = lane >> 2;          // staging: 4 lanes/row (64 B rows), 16 rows/instr
    const int ch = lane & 3;           // 16B chunk within row
    const int csrc = ((ch ^ ((rg >> 1) & 3)) << 3);
    const int xo   = ((quad ^ ((lm >> 1) & 3)) << 3);
    const int wcol = wave * 64;        // this wave's 64-col band

    f32x4 acc[4][4];
    #pragma unroll
    for (int i = 0; i < 4; ++i)
        #pragma unroll
        for (int j = 0; j < 4; ++j) acc[i][j] = (f32x4)0.0f;

    const int T = nseg * 8;            // K-steps of 32 (K=256/seg)

    auto stage = [&](int t, int b) {
        const int seg = t >> 3;
        const int k0 = (t & 7) * 32;
        const u16* Aseg = (seg == 0) ? A0 : (seg == 1) ? A1 : A2;
        const u16* Bseg = (seg == 0) ? B0 : (seg == 1) ? B1 : B2;
        {   // A: 64 rows, wave stages its own 16
            int lr = wave * 16;
            int grow = n0 + lr + rg; if (grow > N - 1) grow = N - 1;
            gl2lds16(Aseg + (size_t)grow * H_DIM + k0 + csrc, &As[b][lr * 32]);
        }
        #pragma unroll
        for (int i = 0; i < 4; ++i) {   // B: 256 rows, wave stages 64
            int lr = wave * 64 + i * 16;
            gl2lds16(Bseg + (size_t)(lr + rg) * H_DIM + k0 + csrc, &Bs[b][lr * 32]);
        }
    };

    stage(0, 0);
    for (int t = 0; t < T; ++t) {
        if (t + 1 < T) {
            stage(t + 1, (t + 1) & 1);
            asm volatile("s_waitcnt vmcnt(5)" ::: "memory");  // tile t landed; t+1 in flight
        } else {
            asm volatile("s_waitcnt vmcnt(0)" ::: "memory");
        }
        __builtin_amdgcn_s_barrier();
        __builtin_amdgcn_sched_barrier(0);

        const u16* ap = &As[t & 1][0];
        const u16* bp = &Bs[t & 1][0];
        bf16x8 af[4], bfr[4];
        #pragma unroll
        for (int i = 0; i < 4; ++i)
            af[i] = *(const bf16x8*)&ap[(i * 16 + lm) * 32 + xo];
        #pragma unroll
        for (int j = 0; j < 4; ++j)
            bfr[j] = *(const bf16x8*)&bp[(wcol + j * 16 + lm) * 32 + xo];
        #pragma unroll
        for (int i = 0; i < 4; ++i)
            #pragma unroll
            for (int j = 0; j < 4; ++j)
                acc[i][j] = __builtin_amdgcn_mfma_f32_16x16x32_bf16(af[i], bfr[j], acc[i][j], 0, 0, 0);

        __builtin_amdgcn_sched_barrier(0);
        __builtin_amdgcn_s_barrier();
        __builtin_amdgcn_sched_barrier(0);
    }

    // ---- epilogue: relu+bias, +residual H, LN over 256 cols (cross-wave), write bf16 ----
    // lnred aliases dead As space (k-loop finished at the barrier above).
    float* lnred = reinterpret_cast<float*>(&As[0][0]);   // [wave*64+lrow]*2 + {0,1}; 2 KB
    float bj[4];
    #pragma unroll
    for (int j = 0; j < 4; ++j) bj[j] = bias[wcol + j * 16 + lm];

    // pass 1: per-row partial (sum, sumsq) over this wave's 64 cols
    #pragma unroll
    for (int i = 0; i < 4; ++i) {
        #pragma unroll
        for (int r = 0; r < 4; ++r) {
            int lrow = i * 16 + quad * 4 + r;
            int grow = n0 + lrow;
            int hrow = (grow < N) ? grow : (N - 1);   // clamp: garbage rows never written
            float s = 0.f, q = 0.f;
            #pragma unroll
            for (int j = 0; j < 4; ++j) {
                int col = wcol + j * 16 + lm;
                float x = fmaxf(acc[i][j][r] + bj[j], 0.f)
                        + bf2f(H[(size_t)hrow * H_DIM + col]);
                s += x; q += x * x;
            }
            #pragma unroll
            for (int off = 1; off < 16; off <<= 1) {
                s += __shfl_xor(s, off, 64);
                q += __shfl_xor(q, off, 64);
            }
            if (lm == 0) {
                lnred[(wave * 64 + lrow) * 2 + 0] = s;
                lnred[(wave * 64 + lrow) * 2 + 1] = q;
            }
        }
    }
    __syncthreads();

    // pass 2: finalize LN for own quarter, write bf16
    #pragma unroll
    for (int i = 0; i < 4; ++i) {
        #pragma unroll
        for (int r = 0; r < 4; ++r) {
            int lrow = i * 16 + quad * 4 + r;
            int grow = n0 + lrow;
            if (grow >= N) continue;
            float s = lnred[(0 * 64 + lrow) * 2 + 0] + lnred[(1 * 64 + lrow) * 2 + 0]
                    + lnred[(2 * 64 + lrow) * 2 + 0] + lnred[(3 * 64 + lrow) * 2 + 0];
            float q = lnred[(0 * 64 + lrow) * 2 + 1] + lnred[(1 * 64 + lrow) * 2 + 1]
                    + lnred[(2 * 64 + lrow) * 2 + 1] + lnred[(3 * 64 + lrow) * 2 + 1];
            float mean = s * (1.0f / H_DIM);
            float var  = q * (1.0f / H_DIM) - mean * mean;
            float inv  = rsqrtf(var + EPS_LN);
            #pragma unroll
            for (int j = 0; j < 4; ++j) {
                int col = wcol + j * 16 + lm;
                float x = fmaxf(acc[i][j][r] + bj[j], 0.f)
                        + bf2f(H[(size_t)grow * H_DIM + col]);
                H[(size_t)grow * H_DIM + col] = f2bf((x - mean) * inv * lng[col] + lnb[col]);
            }
        }
    }
}

// ---------------- conversions ----------------
__global__ void xconv_kernel(const float* __restrict__ x, u16* __restrict__ o, int n4)
{
    int i = blockIdx.x * blockDim.x + threadIdx.x;
    if (i >= n4) return;
    float4 v = ((const float4*)x)[i];
    ushort4 u;
    u.x = f2bf(v.x); u.y = f2bf(v.y); u.z = f2bf(v.z); u.w = f2bf(v.w);
    ((ushort4*)o)[i] = u;
}

__global__ void wconv_kernel(const float* __restrict__ W, u16* __restrict__ WT,
                             int K, int M, int count)
{
    int idx = blockIdx.x * blockDim.x + threadIdx.x;
    int per = K * M;
    if (idx >= per * count) return;
    int b = idx / per, rem = idx - b * per;
    int k = rem / M, m = rem - k * M;
    WT[(size_t)b * per + (size_t)m * K + k] = f2bf(W[idx]);
}

__global__ void wsum_kernel(const float* __restrict__ Wself, u16* __restrict__ WT)
{
    int idx = blockIdx.x * blockDim.x + threadIdx.x;
    const int per = H_DIM * H_DIM;
    if (idx >= 2 * per) return;
    int l = idx / per, rem = idx - l * per;
    int k = rem / H_DIM, m = rem - k * H_DIM;
    float v = Wself[(size_t)(l * 3 + 0) * per + rem] + Wself[(size_t)(l * 3 + 1) * per + rem];
    WT[(size_t)l * per + (size_t)m * H_DIM + k] = f2bf(v);
}

__global__ void bsum_kernel(const float* __restrict__ bconv, float* __restrict__ bsum)
{
    int idx = blockIdx.x * blockDim.x + threadIdx.x;
    if (idx >= 2 * H_DIM) return;
    int l = idx >> 8, j = idx & 255;
    bsum[idx] = bconv[(l * 3 + 0) * H_DIM + j] + bconv[(l * 3 + 1) * H_DIM + j];
}

// ---------------- CSR build ----------------
__global__ void degi_kernel(const int* __restrict__ dst, int* __restrict__ deg, int E)
{
    int i = blockIdx.x * blockDim.x + threadIdx.x;
    if (i < E) atomicAdd(&deg[dst[i]], 1);
}

__device__ __forceinline__ int block_exscan256(int val, int* lds, int* total)
{
    int t = threadIdx.x;
    lds[t] = val;
    __syncthreads();
    #pragma unroll
    for (int off = 1; off < 256; off <<= 1) {
        int y = (t >= off) ? lds[t - off] : 0;
        __syncthreads();
        lds[t] += y;
        __syncthreads();
    }
    int inc = lds[t];
    *total = lds[255];
    __syncthreads();
    return inc - val;
}

__global__ void scan1_kernel(const int* __restrict__ in, int* __restrict__ out,
                             int* __restrict__ sums, int n)
{
    __shared__ int lds[256];
    int t = threadIdx.x;
    int base = blockIdx.x * 1024 + t * 4;
    int v0 = 0, v1 = 0, v2 = 0, v3 = 0;
    if (base + 3 < n) {
        int4 q = *(const int4*)(in + base);
        v0 = q.x; v1 = q.y; v2 = q.z; v3 = q.w;
    } else {
        if (base     < n) v0 = in[base];
        if (base + 1 < n) v1 = in[base + 1];
        if (base + 2 < n) v2 = in[base + 2];
    }
    int tot = v0 + v1 + v2 + v3, bt;
    int ex = block_exscan256(tot, lds, &bt);
    if (base     < n) out[base]     = ex;
    if (base + 1 < n) out[base + 1] = ex + v0;
    if (base + 2 < n) out[base + 2] = ex + v0 + v1;
    if (base + 3 < n) out[base + 3] = ex + v0 + v1 + v2;
    if (t == 0) sums[blockIdx.x] = bt;
}

__global__ void scan2_kernel(int* __restrict__ sums, int nc)
{
    __shared__ int lds[256];
    int t = threadIdx.x;
    int v = (t < nc) ? sums[t] : 0;
    int bt;
    int ex = block_exscan256(v, lds, &bt);
    if (t < nc) sums[t] = ex;
}

__global__ void scan3_kernel(int* __restrict__ cur, const int* __restrict__ sums, int n)
{
    int i = blockIdx.x * blockDim.x + threadIdx.x;
    if (i < n) cur[i] += sums[i >> 10];
}

__global__ void csr_fill_kernel(const int* __restrict__ src, const int* __restrict__ dst,
                                int* __restrict__ cur, int* __restrict__ csr, int E)
{
    int e = blockIdx.x * blockDim.x + threadIdx.x;
    if (e < E) {
        int pos = atomicAdd(&cur[dst[e]], 1);
        csr[pos] = src[e];
    }
}

// ---------------- pull-style mean aggregation: 2 dst rows per wave, 16 B/lane ----------------
typedef unsigned short u16x8 __attribute__((ext_vector_type(8)));

__launch_bounds__(256)
__global__ void gather_mean_kernel(const u16* __restrict__ h, const int* __restrict__ cur,
                                   const int* __restrict__ deg, const int* __restrict__ csr,
                                   u16* __restrict__ agg, int N)
{
    int gid = blockIdx.x * blockDim.x + threadIdx.x;
    int d = gid >> 5;
    if (d >= N) return;
    int l = gid & 31;               // 32 chunks of 8 bf16 per 256-wide row
    int dg = deg[d];
    int o  = cur[d] - dg;
    float a[8] = {};
    for (int i = 0; i < dg; ++i) {
        int s = csr[o + i];
        u16x8 v = *(const u16x8*)(h + (size_t)s * H_DIM + l * 8);
        #pragma unroll
        for (int t = 0; t < 8; ++t) a[t] += bf2f(v[t]);
    }
    float r = (dg > 0) ? (1.0f / (float)dg) : 0.f;
    u16x8 u;
    #pragma unroll
    for (int t = 0; t < 8; ++t) u[t] = f2bf(a[t] * r);
    *(u16x8*)(agg + (size_t)d * H_DIM + l * 8) = u;
}

// ---------------- in-place log_softmax ----------------
__launch_bounds__(256)
__global__ void logsoftmax_kernel(float* __restrict__ x, int N, int C)
{
    int gid = blockIdx.x * blockDim.x + threadIdx.x;
    int row = gid >> 6;
    if (row >= N) return;
    int lane = threadIdx.x & 63;
    float v = (lane < C) ? x[(size_t)row * C + lane] : -3.0e38f;
    float m = v;
    #pragma unroll
    for (int off = 32; off; off >>= 1) m = fmaxf(m, __shfl_xor(m, off, 64));
    float e = (lane < C) ? __expf(v - m) : 0.f;
    float s = e;
    #pragma unroll
    for (int off = 32; off; off >>= 1) s += __shfl_xor(s, off, 64);
    float ls = logf(s);
    if (lane < C) x[(size_t)row * C + lane] = v - m - ls;
}

// ======================================================================================
extern "C" void kernel_launch(void* const* d_in, const int* in_sizes, int n_in,
                              void* d_out, int out_size, void* d_ws, size_t ws_size,
                              hipStream_t stream)
{
    const float* x_author = (const float*)d_in[0];
    const float* x_paper  = (const float*)d_in[1];
    const int* e0s = (const int*)d_in[2]; const int* e0d = (const int*)d_in[3];
    const int* e1s = (const int*)d_in[4]; const int* e1d = (const int*)d_in[5];
    const int* e2s = (const int*)d_in[6]; const int* e2d = (const int*)d_in[7];
    const float* embWa = (const float*)d_in[8];  const float* embba = (const float*)d_in[9];
    const float* embWp = (const float*)d_in[10]; const float* embbp = (const float*)d_in[11];
    const float* Wself  = (const float*)d_in[12];
    const float* Wneigh = (const float*)d_in[13];
    const float* bconv  = (const float*)d_in[14];
    const float* lnga = (const float*)d_in[15]; const float* lnba = (const float*)d_in[16];
    const float* lngp = (const float*)d_in[17]; const float* lnbp = (const float*)d_in[18];
    const float* pW1a = (const float*)d_in[19]; const float* pb1a = (const float*)d_in[20];
    const float* pW2a = (const float*)d_in[21]; const float* pb2a = (const float*)d_in[22];
    const float* pW1p = (const float*)d_in[23]; const float* pb1p = (const float*)d_in[24];
    const float* pW2p = (const float*)d_in[25];

    // ---- workspace carve ----
    char* wp = (char*)d_ws;
    auto carveF = [&](size_t n) { float* p = (float*)wp; wp += n * sizeof(float); return p; };
    auto carveU = [&](size_t n) { u16* p = (u16*)wp; wp += n * sizeof(u16); return p; };
    auto carveI = [&](size_t n) { int* p = (int*)wp; wp += n * sizeof(int); return p; };

    float* BSUM = carveF(2 * H_DIM);

    u16* HA16  = carveU((size_t)A_N * H_DIM);
    u16* HP16  = carveU((size_t)P_N * H_DIM);
    u16* AGG0  = carveU((size_t)P_N * H_DIM);
    u16* AGG1  = carveU((size_t)P_N * H_DIM);
    u16* AGGA  = carveU((size_t)A_N * H_DIM);
    u16* XA16  = carveU((size_t)A_N * DIN);
    u16* XP16  = carveU((size_t)P_N * DIN);
    u16* WsT    = carveU(6 * H_DIM * H_DIM);
    u16* WnT    = carveU(6 * H_DIM * H_DIM);
    u16* WsumT  = carveU(2 * H_DIM * H_DIM);
    u16* embWaT = carveU(DIN * H_DIM);
    u16* embWpT = carveU(DIN * H_DIM);
    u16* pW1aT  = carveU(H_DIM * H_DIM);
    u16* pW2aT  = carveU(H_DIM * C_CLS);
    u16* pW1pT  = carveU(H_DIM * H_DIM);
    u16* pW2pT  = carveU(H_DIM * H_DIM);

    int* ideg = carveI(2 * P_N + A_N);
    int* icur = carveI(2 * P_N + A_N);
    int* icsr = carveI(3 * E_N);
    int* isum = carveI(3 * 256);

    int* deg0 = ideg; int* deg1 = deg0 + P_N; int* deg2 = deg1 + P_N;
    int* cur0 = icur; int* cur1 = cur0 + P_N; int* cur2 = cur1 + P_N;
    int* csr0 = icsr; int* csr1 = csr0 + E_N; int* csr2 = csr1 + E_N;
    int* sum0 = isum; int* sum1 = sum0 + 256; int* sum2 = sum1 + 256;

    float* oaOut = (float*)d_out;                  // A_N * C_CLS
    float* opOut = oaOut + (size_t)A_N * C_CLS;    // P_N * H_DIM

    auto gemm = [&](const u16* a0, const u16* b0, const u16* a1, const u16* b1,
                    const u16* a2, const u16* b2, int nseg, const float* bias,
                    float* c32, u16* c16, int N, int K, int M, int relu) {
        dim3 grid((M + GBM - 1) / GBM, (N + GBN - 1) / GBN);
        gemm_mfma2<<<grid, 256, 0, stream>>>(a0, a1, a2, b0, b1, b2, nseg, bias, c32, c16, N, K, M, relu);
    };

    // ---- weight / input conversions ----
    xconv_kernel<<<((A_N * DIN / 4) + 255) / 256, 256, 0, stream>>>(x_author, XA16, A_N * DIN / 4);
    xconv_kernel<<<((P_N * DIN / 4) + 255) / 256, 256, 0, stream>>>(x_paper,  XP16, P_N * DIN / 4);
    wconv_kernel<<<(DIN * H_DIM + 255) / 256, 256, 0, stream>>>(embWa, embWaT, DIN, H_DIM, 1);
    wconv_kernel<<<(DIN * H_DIM + 255) / 256, 256, 0, stream>>>(embWp, embWpT, DIN, H_DIM, 1);
    wconv_kernel<<<(6 * H_DIM * H_DIM + 255) / 256, 256, 0, stream>>>(Wself,  WsT, H_DIM, H_DIM, 6);
    wconv_kernel<<<(6 * H_DIM * H_DIM + 255) / 256, 256, 0, stream>>>(Wneigh, WnT, H_DIM, H_DIM, 6);
    wsum_kernel<<<(2 * H_DIM * H_DIM + 255) / 256, 256, 0, stream>>>(Wself, WsumT);
    bsum_kernel<<<2, 256, 0, stream>>>(bconv, BSUM);
    wconv_kernel<<<(H_DIM * H_DIM + 255) / 256, 256, 0, stream>>>(pW1a, pW1aT, H_DIM, H_DIM, 1);
    wconv_kernel<<<(H_DIM * C_CLS + 255) / 256, 256, 0, stream>>>(pW2a, pW2aT, H_DIM, C_CLS, 1);
    wconv_kernel<<<(H_DIM * H_DIM + 255) / 256, 256, 0, stream>>>(pW1p, pW1pT, H_DIM, H_DIM, 1);
    wconv_kernel<<<(H_DIM * H_DIM + 255) / 256, 256, 0, stream>>>(pW2p, pW2pT, H_DIM, H_DIM, 1);

    // ---- CSR build ----
    hipMemsetAsync(ideg, 0, (size_t)(2 * P_N + A_N) * sizeof(int), stream);
    const int eB = (E_N + 255) / 256;
    degi_kernel<<<eB, 256, 0, stream>>>(e0d, deg0, E_N);
    degi_kernel<<<eB, 256, 0, stream>>>(e1d, deg1, E_N);
    degi_kernel<<<eB, 256, 0, stream>>>(e2d, deg2, E_N);

    auto build_scan = [&](int* deg, int* cur, int* sums, int n) {
        int nc = (n + 1023) / 1024;
        scan1_kernel<<<nc, 256, 0, stream>>>(deg, cur, sums, n);
        scan2_kernel<<<1, 256, 0, stream>>>(sums, nc);
        scan3_kernel<<<(n + 255) / 256, 256, 0, stream>>>(cur, sums, n);
    };
    build_scan(deg0, cur0, sum0, P_N);
    build_scan(deg1, cur1, sum1, P_N);
    build_scan(deg2, cur2, sum2, A_N);

    csr_fill_kernel<<<eB, 256, 0, stream>>>(e0s, e0d, cur0, csr0, E_N);
    csr_fill_kernel<<<eB, 256, 0, stream>>>(e1s, e1d, cur1, csr1, E_N);
    csr_fill_kernel<<<eB, 256, 0, stream>>>(e2s, e2d, cur2, csr2, E_N);

    // ---- input embeddings (bf16 out) ----
    gemm(XA16, embWaT, 0, 0, 0, 0, 1, embba, nullptr, HA16, A_N, DIN, H_DIM, 0);
    gemm(XP16, embWpT, 0, 0, 0, 0, 1, embbp, nullptr, HP16, P_N, DIN, H_DIM, 0);

    const int gaBlkP = (P_N * 32 + 255) / 256;
    const int gaBlkA = (A_N * 32 + 255) / 256;
    const size_t W2 = (size_t)H_DIM * H_DIM;

    for (int l = 0; l < 2; ++l) {
        // aggregations (read pre-update H)
        gather_mean_kernel<<<gaBlkP, 256, 0, stream>>>(HA16, cur0, deg0, csr0, AGG0, P_N);
        gather_mean_kernel<<<gaBlkP, 256, 0, stream>>>(HP16, cur1, deg1, csr1, AGG1, P_N);
        gather_mean_kernel<<<gaBlkA, 256, 0, stream>>>(HP16, cur2, deg2, csr2, AGGA, A_N);

        // paper: hp@(Ws0+Ws1) + agg0@Wn0 + agg1@Wn1 + (b0+b1), then relu+residual+LN in-place
        gemm_ln<<<(P_N + 63) / 64, 256, 0, stream>>>(
            HP16, AGG0, AGG1,
            WsumT + (size_t)l * W2, WnT + (size_t)(l * 3 + 0) * W2, WnT + (size_t)(l * 3 + 1) * W2,
            3, BSUM + l * H_DIM, lngp, lnbp, HP16, P_N);

        // author: ha@Ws2 + aggA@Wn2 + b2, then relu+residual+LN in-place
        gemm_ln<<<(A_N + 63) / 64, 256, 0, stream>>>(
            HA16, AGGA, (const u16*)nullptr,
            WsT + (size_t)(l * 3 + 2) * W2, WnT + (size_t)(l * 3 + 2) * W2, (const u16*)nullptr,
            2, bconv + (size_t)(l * 3 + 2) * H_DIM, lnga, lnba, HA16, A_N);
    }

    // ---- output heads ----
    u16* TMPA16 = AGGA;   // free after layers
    u16* TMPP16 = AGG0;
    gemm(HA16, pW1aT, 0, 0, 0, 0, 1, pb1a, nullptr, TMPA16, A_N, H_DIM, H_DIM, 1);
    gemm(TMPA16, pW2aT, 0, 0, 0, 0, 1, pb2a, oaOut, nullptr, A_N, H_DIM, C_CLS, 0);
    logsoftmax_kernel<<<(A_N * 64 + 255) / 256, 256, 0, stream>>>(oaOut, A_N, C_CLS);

    gemm(HP16, pW1pT, 0, 0, 0, 0, 1, pb1p, nullptr, TMPP16, P_N, H_DIM, H_DIM, 1);
    gemm(TMPP16, pW2pT, 0, 0, 0, 0, 1, nullptr, opOut, nullptr, P_N, H_DIM, H_DIM, 0);
}

// Round 7
// 1158.681 us; speedup vs baseline: 1.2446x; 1.2446x over previous
//
#include <hip/hip_runtime.h>

#define A_N   50000
#define P_N   100000
#define DIN   128
#define H_DIM 256
#define C_CLS 40
#define E_N   300000
#define EPS_LN 1e-5f

typedef short bf16x8 __attribute__((ext_vector_type(8)));
typedef float f32x4  __attribute__((ext_vector_type(4)));
typedef unsigned short u16;

__device__ __forceinline__ u16 f2bf(float x) {
    union { float f; unsigned u; } v; v.f = x;
    unsigned r = v.u + 0x7fff + ((v.u >> 16) & 1);
    return (u16)(r >> 16);
}
__device__ __forceinline__ float bf2f(u16 h) {
    union { unsigned u; float f; } v; v.u = ((unsigned)h) << 16;
    return v.f;
}

// async global->LDS, 16 B per lane; lds base must be wave-uniform (HW scatters lane*16)
__device__ __forceinline__ void gl2lds16(const u16* g, u16* ldsbase) {
    __builtin_amdgcn_global_load_lds(
        (const __attribute__((address_space(1))) unsigned int*)g,
        (__attribute__((address_space(3))) unsigned int*)ldsbase, 16, 0, 0);
}

// NOTE (session evidence): do NOT swizzle the gl2lds global source. Both source-swizzled
// variants (v2, v6) regressed hard despite SQ_LDS_BANK_CONFLICT -> 0; linear-source
// versions (v1, v5) are fastest.  The ~1e7 conflict-cycles of the linear layout are
// benign (~4 cyc/read avg); the permuted per-lane source appears to defeat gl2lds
// coalescing (v6: FETCH +16MB, WRITE +61MB, time 2x).

// ================= general bf16 MFMA GEMM: C[N,M] = sum_seg A_seg[N,K] @ (BT_seg[M,K])^T ======
// v7: counted-vmcnt double-buffer (v5-proven transform), addresses identical to original.
// 128x128 tile, BK=32, 256 threads (4 waves), wave = 64x64 via 4x4 of 16x16x32 MFMA.
#define GBN 128
#define GBM 128

__launch_bounds__(256)
__global__ void gemm_mfma2(const u16* __restrict__ A0, const u16* __restrict__ A1,
                           const u16* __restrict__ A2,
                           const u16* __restrict__ B0, const u16* __restrict__ B1,
                           const u16* __restrict__ B2,
                           int nseg, const float* __restrict__ bias,
                           float* __restrict__ C32, u16* __restrict__ C16,
                           int N, int K, int M, int relu)
{
    __shared__ u16 As[2][GBN * 32];   // 2 x 8 KB
    __shared__ u16 Bs[2][GBM * 32];   // 2 x 8 KB

    const int tid  = threadIdx.x;
    const int wave = tid >> 6;
    const int lane = tid & 63;
    const int n0 = blockIdx.y * GBN;
    const int m0 = blockIdx.x * GBM;
    const int wrow = (wave >> 1) * 64;
    const int wcol = (wave & 1) * 64;
    const int lm   = lane & 15;
    const int quad = lane >> 4;
    const int rg = lane >> 2;      // staging: 4 lanes/row (64 B rows), 16 rows/instr
    const int ch = lane & 3;       // 16B chunk within row

    f32x4 acc[4][4];
    #pragma unroll
    for (int i = 0; i < 4; ++i)
        #pragma unroll
        for (int j = 0; j < 4; ++j)
            acc[i][j] = (f32x4)0.0f;

    const int ks = K >> 5;         // K-steps per segment
    const int T  = nseg * ks;

    auto stage = [&](int t, int b) {
        int seg = 0, tt = t;
        while (tt >= ks) { tt -= ks; ++seg; }   // nseg <= 3
        const int k0 = tt * 32;
        const u16* Aseg = (seg == 0) ? A0 : (seg == 1) ? A1 : A2;
        const u16* Bseg = (seg == 0) ? B0 : (seg == 1) ? B1 : B2;
        #pragma unroll
        for (int i = 0; i < 2; ++i) {
            int lr = wave * 32 + i * 16;
            int grow = n0 + lr + rg; if (grow > N - 1) grow = N - 1;
            gl2lds16(Aseg + (size_t)grow * K + k0 + ch * 8, &As[b][lr * 32]);
        }
        #pragma unroll
        for (int i = 0; i < 2; ++i) {
            int lr = wave * 32 + i * 16;
            int brow = m0 + lr + rg; if (brow > M - 1) brow = M - 1;
            gl2lds16(Bseg + (size_t)brow * K + k0 + ch * 8, &Bs[b][lr * 32]);
        }
    };

    stage(0, 0);
    for (int t = 0; t < T; ++t) {
        if (t + 1 < T) {
            stage(t + 1, (t + 1) & 1);
            asm volatile("s_waitcnt vmcnt(4)" ::: "memory");  // tile t landed; t+1 in flight
        } else {
            asm volatile("s_waitcnt vmcnt(0)" ::: "memory");
        }
        __builtin_amdgcn_s_barrier();
        __builtin_amdgcn_sched_barrier(0);

        const u16* ap = &As[t & 1][0];
        const u16* bp = &Bs[t & 1][0];
        bf16x8 af[4], bfr[4];
        #pragma unroll
        for (int i = 0; i < 4; ++i)
            af[i] = *(const bf16x8*)&ap[(wrow + i * 16 + lm) * 32 + quad * 8];
        #pragma unroll
        for (int j = 0; j < 4; ++j)
            bfr[j] = *(const bf16x8*)&bp[(wcol + j * 16 + lm) * 32 + quad * 8];
        #pragma unroll
        for (int i = 0; i < 4; ++i)
            #pragma unroll
            for (int j = 0; j < 4; ++j)
                acc[i][j] = __builtin_amdgcn_mfma_f32_16x16x32_bf16(af[i], bfr[j], acc[i][j], 0, 0, 0);

        __builtin_amdgcn_sched_barrier(0);
        __builtin_amdgcn_s_barrier();
        __builtin_amdgcn_sched_barrier(0);
    }

    // epilogue: C/D layout col=lane&15, row=quad*4+reg
    float bj[4];
    #pragma unroll
    for (int j = 0; j < 4; ++j) {
        int gcol = m0 + wcol + j * 16 + lm;
        bj[j] = (bias && gcol < M) ? bias[gcol] : 0.f;
    }
    #pragma unroll
    for (int i = 0; i < 4; ++i) {
        #pragma unroll
        for (int r = 0; r < 4; ++r) {
            int grow = n0 + wrow + i * 16 + quad * 4 + r;
            if (grow >= N) continue;
            #pragma unroll
            for (int j = 0; j < 4; ++j) {
                int gcol = m0 + wcol + j * 16 + lm;
                if (gcol >= M) continue;
                float v = acc[i][j][r] + bj[j];
                if (relu) v = fmaxf(v, 0.f);
                if (C32) C32[(size_t)grow * M + gcol] = v;
                if (C16) C16[(size_t)grow * M + gcol] = f2bf(v);
            }
        }
    }
}

// ========== fused layer GEMM + relu + residual + LayerNorm, in-place on H (bf16) ==========
// v5 (verified 103 us): v1's geometry + epilogue (64 rows/block, 16r x 256c per wave,
// BK=32, acc[16]) with counted-vmcnt double-buffering:
//   - As[2]/Bs[2] double buffers (40 KB -> 4 blocks/CU).
//   - per step: stage(t+1) -> s_waitcnt vmcnt(5) (tile t landed, t+1 in flight; never
//     drains to 0 mid-loop) -> s_barrier -> compute t -> s_barrier.
//   - sched_barrier(0) pins ds_read/MFMA inside their phase (rule #18).
__launch_bounds__(256)
__global__ void gemm_ln(const u16* __restrict__ A0, const u16* __restrict__ A1,
                        const u16* __restrict__ A2,
                        const u16* __restrict__ B0, const u16* __restrict__ B1,
                        const u16* __restrict__ B2,
                        int nseg, const float* __restrict__ bias,
                        const float* __restrict__ lng, const float* __restrict__ lnb,
                        u16* __restrict__ H, int N)
{
    __shared__ u16 As[2][64 * 32];    // 2 x 4 KB
    __shared__ u16 Bs[2][256 * 32];   // 2 x 16 KB

    const int tid  = threadIdx.x;
    const int wave = tid >> 6;
    const int lane = tid & 63;
    const int n0 = blockIdx.x * 64;
    const int lm   = lane & 15;
    const int quad = lane >> 4;
    const int rg = lane >> 2;          // staging: 4 lanes/row (64 B rows), 16 rows/instr
    const int ch = lane & 3;           // 16B chunk within row

    f32x4 acc[16];
    #pragma unroll
    for (int j = 0; j < 16; ++j) acc[j] = (f32x4)0.0f;

    const int T = nseg * 8;            // K-steps of 32 (K=256/seg)

    auto stage = [&](int t, int b) {
        const int seg = t >> 3;
        const int k0 = (t & 7) * 32;
        const u16* Aseg = (seg == 0) ? A0 : (seg == 1) ? A1 : A2;
        const u16* Bseg = (seg == 0) ? B0 : (seg == 1) ? B1 : B2;
        {   // A: 64 rows, wave stages its own 16
            int lr = wave * 16;
            int grow = n0 + lr + rg; if (grow > N - 1) grow = N - 1;
            gl2lds16(Aseg + (size_t)grow * H_DIM + k0 + ch * 8, &As[b][lr * 32]);
        }
        #pragma unroll
        for (int i = 0; i < 4; ++i) {   // B: 256 rows, wave stages 64
            int lr = wave * 64 + i * 16;
            gl2lds16(Bseg + (size_t)(lr + rg) * H_DIM + k0 + ch * 8, &Bs[b][lr * 32]);
        }
    };

    stage(0, 0);
    for (int t = 0; t < T; ++t) {
        if (t + 1 < T) {
            stage(t + 1, (t + 1) & 1);
            asm volatile("s_waitcnt vmcnt(5)" ::: "memory");  // tile t landed; t+1 in flight
        } else {
            asm volatile("s_waitcnt vmcnt(0)" ::: "memory");  // last tile: drain
        }
        __builtin_amdgcn_s_barrier();          // all waves' tile-t loads visible
        __builtin_amdgcn_sched_barrier(0);     // no ds_read hoists above this point

        const u16* ap = &As[t & 1][0];
        const u16* bp = &Bs[t & 1][0];
        bf16x8 af = *(const bf16x8*)&ap[(wave * 16 + lm) * 32 + quad * 8];
        #pragma unroll
        for (int j = 0; j < 16; ++j) {
            bf16x8 bfr = *(const bf16x8*)&bp[(j * 16 + lm) * 32 + quad * 8];
            acc[j] = __builtin_amdgcn_mfma_f32_16x16x32_bf16(af, bfr, acc[j], 0, 0, 0);
        }

        __builtin_amdgcn_sched_barrier(0);     // no ds_read sinks below (buf reused at t+2)
        __builtin_amdgcn_s_barrier();          // all waves done reading buf before restage
        __builtin_amdgcn_sched_barrier(0);
    }

    // epilogue (v1): per row relu + bias, + residual H, LN over 256 cols, write bf16
    #pragma unroll
    for (int r = 0; r < 4; ++r) {
        int grow = n0 + wave * 16 + quad * 4 + r;   // uniform across the 16 lm lanes
        if (grow >= N) continue;
        float v[16];
        float ps = 0.f, pq = 0.f;
        #pragma unroll
        for (int j = 0; j < 16; ++j) {
            int col = j * 16 + lm;
            float x = fmaxf(acc[j][r] + bias[col], 0.f);
            x += bf2f(H[(size_t)grow * H_DIM + col]);
            v[j] = x; ps += x; pq += x * x;
        }
        #pragma unroll
        for (int off = 1; off < 16; off <<= 1) {
            ps += __shfl_xor(ps, off, 64);
            pq += __shfl_xor(pq, off, 64);
        }
        float mean = ps * (1.0f / H_DIM);
        float var  = pq * (1.0f / H_DIM) - mean * mean;
        float inv  = rsqrtf(var + EPS_LN);
        #pragma unroll
        for (int j = 0; j < 16; ++j) {
            int col = j * 16 + lm;
            H[(size_t)grow * H_DIM + col] = f2bf((v[j] - mean) * inv * lng[col] + lnb[col]);
        }
    }
}

// ---------------- conversions ----------------
__global__ void xconv_kernel(const float* __restrict__ x, u16* __restrict__ o, int n4)
{
    int i = blockIdx.x * blockDim.x + threadIdx.x;
    if (i >= n4) return;
    float4 v = ((const float4*)x)[i];
    ushort4 u;
    u.x = f2bf(v.x); u.y = f2bf(v.y); u.z = f2bf(v.z); u.w = f2bf(v.w);
    ((ushort4*)o)[i] = u;
}

__global__ void wconv_kernel(const float* __restrict__ W, u16* __restrict__ WT,
                             int K, int M, int count)
{
    int idx = blockIdx.x * blockDim.x + threadIdx.x;
    int per = K * M;
    if (idx >= per * count) return;
    int b = idx / per, rem = idx - b * per;
    int k = rem / M, m = rem - k * M;
    WT[(size_t)b * per + (size_t)m * K + k] = f2bf(W[idx]);
}

__global__ void wsum_kernel(const float* __restrict__ Wself, u16* __restrict__ WT)
{
    int idx = blockIdx.x * blockDim.x + threadIdx.x;
    const int per = H_DIM * H_DIM;
    if (idx >= 2 * per) return;
    int l = idx / per, rem = idx - l * per;
    int k = rem / H_DIM, m = rem - k * H_DIM;
    float v = Wself[(size_t)(l * 3 + 0) * per + rem] + Wself[(size_t)(l * 3 + 1) * per + rem];
    WT[(size_t)l * per + (size_t)m * H_DIM + k] = f2bf(v);
}

__global__ void bsum_kernel(const float* __restrict__ bconv, float* __restrict__ bsum)
{
    int idx = blockIdx.x * blockDim.x + threadIdx.x;
    if (idx >= 2 * H_DIM) return;
    int l = idx >> 8, j = idx & 255;
    bsum[idx] = bconv[(l * 3 + 0) * H_DIM + j] + bconv[(l * 3 + 1) * H_DIM + j];
}

// ---------------- CSR build ----------------
__global__ void degi_kernel(const int* __restrict__ dst, int* __restrict__ deg, int E)
{
    int i = blockIdx.x * blockDim.x + threadIdx.x;
    if (i < E) atomicAdd(&deg[dst[i]], 1);
}

__device__ __forceinline__ int block_exscan256(int val, int* lds, int* total)
{
    int t = threadIdx.x;
    lds[t] = val;
    __syncthreads();
    #pragma unroll
    for (int off = 1; off < 256; off <<= 1) {
        int y = (t >= off) ? lds[t - off] : 0;
        __syncthreads();
        lds[t] += y;
        __syncthreads();
    }
    int inc = lds[t];
    *total = lds[255];
    __syncthreads();
    return inc - val;
}

__global__ void scan1_kernel(const int* __restrict__ in, int* __restrict__ out,
                             int* __restrict__ sums, int n)
{
    __shared__ int lds[256];
    int t = threadIdx.x;
    int base = blockIdx.x * 1024 + t * 4;
    int v0 = 0, v1 = 0, v2 = 0, v3 = 0;
    if (base + 3 < n) {
        int4 q = *(const int4*)(in + base);
        v0 = q.x; v1 = q.y; v2 = q.z; v3 = q.w;
    } else {
        if (base     < n) v0 = in[base];
        if (base + 1 < n) v1 = in[base + 1];
        if (base + 2 < n) v2 = in[base + 2];
    }
    int tot = v0 + v1 + v2 + v3, bt;
    int ex = block_exscan256(tot, lds, &bt);
    if (base     < n) out[base]     = ex;
    if (base + 1 < n) out[base + 1] = ex + v0;
    if (base + 2 < n) out[base + 2] = ex + v0 + v1;
    if (base + 3 < n) out[base + 3] = ex + v0 + v1 + v2;
    if (t == 0) sums[blockIdx.x] = bt;
}

__global__ void scan2_kernel(int* __restrict__ sums, int nc)
{
    __shared__ int lds[256];
    int t = threadIdx.x;
    int v = (t < nc) ? sums[t] : 0;
    int bt;
    int ex = block_exscan256(v, lds, &bt);
    if (t < nc) sums[t] = ex;
}

__global__ void scan3_kernel(int* __restrict__ cur, const int* __restrict__ sums, int n)
{
    int i = blockIdx.x * blockDim.x + threadIdx.x;
    if (i < n) cur[i] += sums[i >> 10];
}

__global__ void csr_fill_kernel(const int* __restrict__ src, const int* __restrict__ dst,
                                int* __restrict__ cur, int* __restrict__ csr, int E)
{
    int e = blockIdx.x * blockDim.x + threadIdx.x;
    if (e < E) {
        int pos = atomicAdd(&cur[dst[e]], 1);
        csr[pos] = src[e];
    }
}

// ---------------- pull-style mean aggregation: 2 dst rows per wave, 16 B/lane ----------------
typedef unsigned short u16x8 __attribute__((ext_vector_type(8)));

__launch_bounds__(256)
__global__ void gather_mean_kernel(const u16* __restrict__ h, const int* __restrict__ cur,
                                   const int* __restrict__ deg, const int* __restrict__ csr,
                                   u16* __restrict__ agg, int N)
{
    int gid = blockIdx.x * blockDim.x + threadIdx.x;
    int d = gid >> 5;
    if (d >= N) return;
    int l = gid & 31;               // 32 chunks of 8 bf16 per 256-wide row
    int dg = deg[d];
    int o  = cur[d] - dg;
    float a[8] = {};
    for (int i = 0; i < dg; ++i) {
        int s = csr[o + i];
        u16x8 v = *(const u16x8*)(h + (size_t)s * H_DIM + l * 8);
        #pragma unroll
        for (int t = 0; t < 8; ++t) a[t] += bf2f(v[t]);
    }
    float r = (dg > 0) ? (1.0f / (float)dg) : 0.f;
    u16x8 u;
    #pragma unroll
    for (int t = 0; t < 8; ++t) u[t] = f2bf(a[t] * r);
    *(u16x8*)(agg + (size_t)d * H_DIM + l * 8) = u;
}

// ---------------- in-place log_softmax ----------------
__launch_bounds__(256)
__global__ void logsoftmax_kernel(float* __restrict__ x, int N, int C)
{
    int gid = blockIdx.x * blockDim.x + threadIdx.x;
    int row = gid >> 6;
    if (row >= N) return;
    int lane = threadIdx.x & 63;
    float v = (lane < C) ? x[(size_t)row * C + lane] : -3.0e38f;
    float m = v;
    #pragma unroll
    for (int off = 32; off; off >>= 1) m = fmaxf(m, __shfl_xor(m, off, 64));
    float e = (lane < C) ? __expf(v - m) : 0.f;
    float s = e;
    #pragma unroll
    for (int off = 32; off; off >>= 1) s += __shfl_xor(s, off, 64);
    float ls = logf(s);
    if (lane < C) x[(size_t)row * C + lane] = v - m - ls;
}

// ======================================================================================
extern "C" void kernel_launch(void* const* d_in, const int* in_sizes, int n_in,
                              void* d_out, int out_size, void* d_ws, size_t ws_size,
                              hipStream_t stream)
{
    const float* x_author = (const float*)d_in[0];
    const float* x_paper  = (const float*)d_in[1];
    const int* e0s = (const int*)d_in[2]; const int* e0d = (const int*)d_in[3];
    const int* e1s = (const int*)d_in[4]; const int* e1d = (const int*)d_in[5];
    const int* e2s = (const int*)d_in[6]; const int* e2d = (const int*)d_in[7];
    const float* embWa = (const float*)d_in[8];  const float* embba = (const float*)d_in[9];
    const float* embWp = (const float*)d_in[10]; const float* embbp = (const float*)d_in[11];
    const float* Wself  = (const float*)d_in[12];
    const float* Wneigh = (const float*)d_in[13];
    const float* bconv  = (const float*)d_in[14];
    const float* lnga = (const float*)d_in[15]; const float* lnba = (const float*)d_in[16];
    const float* lngp = (const float*)d_in[17]; const float* lnbp = (const float*)d_in[18];
    const float* pW1a = (const float*)d_in[19]; const float* pb1a = (const float*)d_in[20];
    const float* pW2a = (const float*)d_in[21]; const float* pb2a = (const float*)d_in[22];
    const float* pW1p = (const float*)d_in[23]; const float* pb1p = (const float*)d_in[24];
    const float* pW2p = (const float*)d_in[25];

    // ---- workspace carve ----
    char* wp = (char*)d_ws;
    auto carveF = [&](size_t n) { float* p = (float*)wp; wp += n * sizeof(float); return p; };
    auto carveU = [&](size_t n) { u16* p = (u16*)wp; wp += n * sizeof(u16); return p; };
    auto carveI = [&](size_t n) { int* p = (int*)wp; wp += n * sizeof(int); return p; };

    float* BSUM = carveF(2 * H_DIM);

    u16* HA16  = carveU((size_t)A_N * H_DIM);
    u16* HP16  = carveU((size_t)P_N * H_DIM);
    u16* AGG0  = carveU((size_t)P_N * H_DIM);
    u16* AGG1  = carveU((size_t)P_N * H_DIM);
    u16* AGGA  = carveU((size_t)A_N * H_DIM);
    u16* XA16  = carveU((size_t)A_N * DIN);
    u16* XP16  = carveU((size_t)P_N * DIN);
    u16* WsT    = carveU(6 * H_DIM * H_DIM);
    u16* WnT    = carveU(6 * H_DIM * H_DIM);
    u16* WsumT  = carveU(2 * H_DIM * H_DIM);
    u16* embWaT = carveU(DIN * H_DIM);
    u16* embWpT = carveU(DIN * H_DIM);
    u16* pW1aT  = carveU(H_DIM * H_DIM);
    u16* pW2aT  = carveU(H_DIM * C_CLS);
    u16* pW1pT  = carveU(H_DIM * H_DIM);
    u16* pW2pT  = carveU(H_DIM * H_DIM);

    int* ideg = carveI(2 * P_N + A_N);
    int* icur = carveI(2 * P_N + A_N);
    int* icsr = carveI(3 * E_N);
    int* isum = carveI(3 * 256);

    int* deg0 = ideg; int* deg1 = deg0 + P_N; int* deg2 = deg1 + P_N;
    int* cur0 = icur; int* cur1 = cur0 + P_N; int* cur2 = cur1 + P_N;
    int* csr0 = icsr; int* csr1 = csr0 + E_N; int* csr2 = csr1 + E_N;
    int* sum0 = isum; int* sum1 = sum0 + 256; int* sum2 = sum1 + 256;

    float* oaOut = (float*)d_out;                  // A_N * C_CLS
    float* opOut = oaOut + (size_t)A_N * C_CLS;    // P_N * H_DIM

    auto gemm = [&](const u16* a0, const u16* b0, const u16* a1, const u16* b1,
                    const u16* a2, const u16* b2, int nseg, const float* bias,
                    float* c32, u16* c16, int N, int K, int M, int relu) {
        dim3 grid((M + GBM - 1) / GBM, (N + GBN - 1) / GBN);
        gemm_mfma2<<<grid, 256, 0, stream>>>(a0, a1, a2, b0, b1, b2, nseg, bias, c32, c16, N, K, M, relu);
    };

    // ---- weight / input conversions ----
    xconv_kernel<<<((A_N * DIN / 4) + 255) / 256, 256, 0, stream>>>(x_author, XA16, A_N * DIN / 4);
    xconv_kernel<<<((P_N * DIN / 4) + 255) / 256, 256, 0, stream>>>(x_paper,  XP16, P_N * DIN / 4);
    wconv_kernel<<<(DIN * H_DIM + 255) / 256, 256, 0, stream>>>(embWa, embWaT, DIN, H_DIM, 1);
    wconv_kernel<<<(DIN * H_DIM + 255) / 256, 256, 0, stream>>>(embWp, embWpT, DIN, H_DIM, 1);
    wconv_kernel<<<(6 * H_DIM * H_DIM + 255) / 256, 256, 0, stream>>>(Wself,  WsT, H_DIM, H_DIM, 6);
    wconv_kernel<<<(6 * H_DIM * H_DIM + 255) / 256, 256, 0, stream>>>(Wneigh, WnT, H_DIM, H_DIM, 6);
    wsum_kernel<<<(2 * H_DIM * H_DIM + 255) / 256, 256, 0, stream>>>(Wself, WsumT);
    bsum_kernel<<<2, 256, 0, stream>>>(bconv, BSUM);
    wconv_kernel<<<(H_DIM * H_DIM + 255) / 256, 256, 0, stream>>>(pW1a, pW1aT, H_DIM, H_DIM, 1);
    wconv_kernel<<<(H_DIM * C_CLS + 255) / 256, 256, 0, stream>>>(pW2a, pW2aT, H_DIM, C_CLS, 1);
    wconv_kernel<<<(H_DIM * H_DIM + 255) / 256, 256, 0, stream>>>(pW1p, pW1pT, H_DIM, H_DIM, 1);
    wconv_kernel<<<(H_DIM * H_DIM + 255) / 256, 256, 0, stream>>>(pW2p, pW2pT, H_DIM, H_DIM, 1);

    // ---- CSR build ----
    hipMemsetAsync(ideg, 0, (size_t)(2 * P_N + A_N) * sizeof(int), stream);
    const int eB = (E_N + 255) / 256;
    degi_kernel<<<eB, 256, 0, stream>>>(e0d, deg0, E_N);
    degi_kernel<<<eB, 256, 0, stream>>>(e1d, deg1, E_N);
    degi_kernel<<<eB, 256, 0, stream>>>(e2d, deg2, E_N);

    auto build_scan = [&](int* deg, int* cur, int* sums, int n) {
        int nc = (n + 1023) / 1024;
        scan1_kernel<<<nc, 256, 0, stream>>>(deg, cur, sums, n);
        scan2_kernel<<<1, 256, 0, stream>>>(sums, nc);
        scan3_kernel<<<(n + 255) / 256, 256, 0, stream>>>(cur, sums, n);
    };
    build_scan(deg0, cur0, sum0, P_N);
    build_scan(deg1, cur1, sum1, P_N);
    build_scan(deg2, cur2, sum2, A_N);

    csr_fill_kernel<<<eB, 256, 0, stream>>>(e0s, e0d, cur0, csr0, E_N);
    csr_fill_kernel<<<eB, 256, 0, stream>>>(e1s, e1d, cur1, csr1, E_N);
    csr_fill_kernel<<<eB, 256, 0, stream>>>(e2s, e2d, cur2, csr2, E_N);

    // ---- input embeddings (bf16 out) ----
    gemm(XA16, embWaT, 0, 0, 0, 0, 1, embba, nullptr, HA16, A_N, DIN, H_DIM, 0);
    gemm(XP16, embWpT, 0, 0, 0, 0, 1, embbp, nullptr, HP16, P_N, DIN, H_DIM, 0);

    const int gaBlkP = (P_N * 32 + 255) / 256;
    const int gaBlkA = (A_N * 32 + 255) / 256;
    const size_t W2 = (size_t)H_DIM * H_DIM;

    for (int l = 0; l < 2; ++l) {
        // aggregations (read pre-update H)
        gather_mean_kernel<<<gaBlkP, 256, 0, stream>>>(HA16, cur0, deg0, csr0, AGG0, P_N);
        gather_mean_kernel<<<gaBlkP, 256, 0, stream>>>(HP16, cur1, deg1, csr1, AGG1, P_N);
        gather_mean_kernel<<<gaBlkA, 256, 0, stream>>>(HP16, cur2, deg2, csr2, AGGA, A_N);

        // paper: hp@(Ws0+Ws1) + agg0@Wn0 + agg1@Wn1 + (b0+b1), then relu+residual+LN in-place
        gemm_ln<<<(P_N + 63) / 64, 256, 0, stream>>>(
            HP16, AGG0, AGG1,
            WsumT + (size_t)l * W2, WnT + (size_t)(l * 3 + 0) * W2, WnT + (size_t)(l * 3 + 1) * W2,
            3, BSUM + l * H_DIM, lngp, lnbp, HP16, P_N);

        // author: ha@Ws2 + aggA@Wn2 + b2, then relu+residual+LN in-place
        gemm_ln<<<(A_N + 63) / 64, 256, 0, stream>>>(
            HA16, AGGA, (const u16*)nullptr,
            WsT + (size_t)(l * 3 + 2) * W2, WnT + (size_t)(l * 3 + 2) * W2, (const u16*)nullptr,
            2, bconv + (size_t)(l * 3 + 2) * H_DIM, lnga, lnba, HA16, A_N);
    }

    // ---- output heads ----
    u16* TMPA16 = AGGA;   // free after layers
    u16* TMPP16 = AGG0;
    gemm(HA16, pW1aT, 0, 0, 0, 0, 1, pb1a, nullptr, TMPA16, A_N, H_DIM, H_DIM, 1);
    gemm(TMPA16, pW2aT, 0, 0, 0, 0, 1, pb2a, oaOut, nullptr, A_N, H_DIM, C_CLS, 0);
    logsoftmax_kernel<<<(A_N * 64 + 255) / 256, 256, 0, stream>>>(oaOut, A_N, C_CLS);

    gemm(HP16, pW1pT, 0, 0, 0, 0, 1, pb1p, nullptr, TMPP16, P_N, H_DIM, H_DIM, 1);
    gemm(TMPP16, pW2pT, 0, 0, 0, 0, 1, nullptr, opOut, nullptr, P_N, H_DIM, H_DIM, 0);
}

// Round 9
// 1066.156 us; speedup vs baseline: 1.3526x; 1.0868x over previous
//
#include <hip/hip_runtime.h>

#define A_N   50000
#define P_N   100000
#define DIN   128
#define H_DIM 256
#define C_CLS 40
#define E_N   300000
#define EPS_LN 1e-5f

typedef short bf16x8 __attribute__((ext_vector_type(8)));
typedef float f32x4  __attribute__((ext_vector_type(4)));
typedef unsigned short u16;

__device__ __forceinline__ u16 f2bf(float x) {
    union { float f; unsigned u; } v; v.f = x;
    unsigned r = v.u + 0x7fff + ((v.u >> 16) & 1);
    return (u16)(r >> 16);
}
__device__ __forceinline__ float bf2f(u16 h) {
    union { unsigned u; float f; } v; v.u = ((unsigned)h) << 16;
    return v.f;
}

// async global->LDS, 16 B per lane; lds base must be wave-uniform (HW scatters lane*16)
__device__ __forceinline__ void gl2lds16(const u16* g, u16* ldsbase) {
    __builtin_amdgcn_global_load_lds(
        (const __attribute__((address_space(1))) unsigned int*)g,
        (__attribute__((address_space(3))) unsigned int*)ldsbase, 16, 0, 0);
}

// SESSION LEDGER (do not re-try without new evidence):
//  - gl2lds source-swizzle: REGRESSED 2x (v2 132us, v6 205us) despite conflicts->0;
//    linear source is mandatory (coalescer).
//  - bigger tiles / more acc regs (128): REGRESSED via occupancy/spill (v2, v3).
//  - 64x64 wave geometry (8 reads/16 MFMA): REGRESSED vs 16x256 (v4, v6).
//  - counted-vmcnt dbuf on gemm_ln: WON (+9%, v5 103us vs v1 112us).
//  - same transform on gemm_mfma2: ~neutral (v7), and v7's co-compiled gemm_ln ran
//    103->127us on IDENTICAL source (rule #19 perturbation or cross-run noise).
//  - THIS ROUND: byte-identical resubmission of round-5 source (measured best, 1068us)
//    as A/A reproducibility test + revert of the unvalidated mfma2 dbuf.
//    (Round-8 attempt of this same source died to an infra flake; resubmitting.)

// ================= general bf16 MFMA GEMM: C[N,M] = sum_seg A_seg[N,K] @ (BT_seg[M,K])^T ======
// 128x128 tile, BK=32, 256 threads (4 waves), wave = 64x64 via 4x4 of 16x16x32 MFMA.
// LDS [row][32] unpadded (global_load_lds layout); frag b128 reads are bank-balanced.
#define GBN 128
#define GBM 128

__launch_bounds__(256)
__global__ void gemm_mfma2(const u16* __restrict__ A0, const u16* __restrict__ A1,
                           const u16* __restrict__ A2,
                           const u16* __restrict__ B0, const u16* __restrict__ B1,
                           const u16* __restrict__ B2,
                           int nseg, const float* __restrict__ bias,
                           float* __restrict__ C32, u16* __restrict__ C16,
                           int N, int K, int M, int relu)
{
    __shared__ u16 As[GBN * 32];   // 8 KB
    __shared__ u16 Bs[GBM * 32];   // 8 KB

    const int tid  = threadIdx.x;
    const int wave = tid >> 6;
    const int lane = tid & 63;
    const int n0 = blockIdx.y * GBN;
    const int m0 = blockIdx.x * GBM;
    const int wrow = (wave >> 1) * 64;
    const int wcol = (wave & 1) * 64;
    const int lm   = lane & 15;
    const int quad = lane >> 4;
    const int rg = lane >> 2;      // staging: 4 lanes/row (64 B rows), 16 rows/instr
    const int ch = lane & 3;       // 16B chunk within row

    f32x4 acc[4][4];
    #pragma unroll
    for (int i = 0; i < 4; ++i)
        #pragma unroll
        for (int j = 0; j < 4; ++j)
            acc[i][j] = (f32x4)0.0f;

    for (int seg = 0; seg < nseg; ++seg) {
        const u16* Aseg = (seg == 0) ? A0 : (seg == 1) ? A1 : A2;
        const u16* Bseg = (seg == 0) ? B0 : (seg == 1) ? B1 : B2;

        for (int k0 = 0; k0 < K; k0 += 32) {
            __syncthreads();   // previous tile fully consumed before overwrite
            #pragma unroll
            for (int i = 0; i < 2; ++i) {
                int lr = wave * 32 + i * 16;
                int grow = n0 + lr + rg; if (grow > N - 1) grow = N - 1;
                gl2lds16(Aseg + (size_t)grow * K + k0 + ch * 8, &As[lr * 32]);
            }
            #pragma unroll
            for (int i = 0; i < 2; ++i) {
                int lr = wave * 32 + i * 16;
                int brow = m0 + lr + rg; if (brow > M - 1) brow = M - 1;
                gl2lds16(Bseg + (size_t)brow * K + k0 + ch * 8, &Bs[lr * 32]);
            }
            __syncthreads();   // vmcnt drain + barrier

            bf16x8 af[4], bfr[4];
            #pragma unroll
            for (int i = 0; i < 4; ++i)
                af[i] = *(const bf16x8*)&As[(wrow + i * 16 + lm) * 32 + quad * 8];
            #pragma unroll
            for (int j = 0; j < 4; ++j)
                bfr[j] = *(const bf16x8*)&Bs[(wcol + j * 16 + lm) * 32 + quad * 8];
            #pragma unroll
            for (int i = 0; i < 4; ++i)
                #pragma unroll
                for (int j = 0; j < 4; ++j)
                    acc[i][j] = __builtin_amdgcn_mfma_f32_16x16x32_bf16(af[i], bfr[j], acc[i][j], 0, 0, 0);
        }
    }

    // epilogue: C/D layout col=lane&15, row=quad*4+reg
    float bj[4];
    #pragma unroll
    for (int j = 0; j < 4; ++j) {
        int gcol = m0 + wcol + j * 16 + lm;
        bj[j] = (bias && gcol < M) ? bias[gcol] : 0.f;
    }
    #pragma unroll
    for (int i = 0; i < 4; ++i) {
        #pragma unroll
        for (int r = 0; r < 4; ++r) {
            int grow = n0 + wrow + i * 16 + quad * 4 + r;
            if (grow >= N) continue;
            #pragma unroll
            for (int j = 0; j < 4; ++j) {
                int gcol = m0 + wcol + j * 16 + lm;
                if (gcol >= M) continue;
                float v = acc[i][j][r] + bj[j];
                if (relu) v = fmaxf(v, 0.f);
                if (C32) C32[(size_t)grow * M + gcol] = v;
                if (C16) C16[(size_t)grow * M + gcol] = f2bf(v);
            }
        }
    }
}

// ========== fused layer GEMM + relu + residual + LayerNorm, in-place on H (bf16) ==========
// v5 (verified 103 us): v1's geometry + epilogue (64 rows/block, 16r x 256c per wave,
// BK=32, acc[16]) with counted-vmcnt double-buffering:
//   - As[2]/Bs[2] double buffers (40 KB -> 4 blocks/CU).
//   - per step: stage(t+1) -> s_waitcnt vmcnt(5) (tile t landed, t+1 in flight; never
//     drains to 0 mid-loop) -> s_barrier -> compute t -> s_barrier.
//   - sched_barrier(0) pins ds_read/MFMA inside their phase (rule #18).
__launch_bounds__(256)
__global__ void gemm_ln(const u16* __restrict__ A0, const u16* __restrict__ A1,
                        const u16* __restrict__ A2,
                        const u16* __restrict__ B0, const u16* __restrict__ B1,
                        const u16* __restrict__ B2,
                        int nseg, const float* __restrict__ bias,
                        const float* __restrict__ lng, const float* __restrict__ lnb,
                        u16* __restrict__ H, int N)
{
    __shared__ u16 As[2][64 * 32];    // 2 x 4 KB
    __shared__ u16 Bs[2][256 * 32];   // 2 x 16 KB

    const int tid  = threadIdx.x;
    const int wave = tid >> 6;
    const int lane = tid & 63;
    const int n0 = blockIdx.x * 64;
    const int lm   = lane & 15;
    const int quad = lane >> 4;
    const int rg = lane >> 2;          // staging: 4 lanes/row (64 B rows), 16 rows/instr
    const int ch = lane & 3;           // 16B chunk within row

    f32x4 acc[16];
    #pragma unroll
    for (int j = 0; j < 16; ++j) acc[j] = (f32x4)0.0f;

    const int T = nseg * 8;            // K-steps of 32 (K=256/seg)

    auto stage = [&](int t, int b) {
        const int seg = t >> 3;
        const int k0 = (t & 7) * 32;
        const u16* Aseg = (seg == 0) ? A0 : (seg == 1) ? A1 : A2;
        const u16* Bseg = (seg == 0) ? B0 : (seg == 1) ? B1 : B2;
        {   // A: 64 rows, wave stages its own 16
            int lr = wave * 16;
            int grow = n0 + lr + rg; if (grow > N - 1) grow = N - 1;
            gl2lds16(Aseg + (size_t)grow * H_DIM + k0 + ch * 8, &As[b][lr * 32]);
        }
        #pragma unroll
        for (int i = 0; i < 4; ++i) {   // B: 256 rows, wave stages 64
            int lr = wave * 64 + i * 16;
            gl2lds16(Bseg + (size_t)(lr + rg) * H_DIM + k0 + ch * 8, &Bs[b][lr * 32]);
        }
    };

    stage(0, 0);
    for (int t = 0; t < T; ++t) {
        if (t + 1 < T) {
            stage(t + 1, (t + 1) & 1);
            asm volatile("s_waitcnt vmcnt(5)" ::: "memory");  // tile t landed; t+1 in flight
        } else {
            asm volatile("s_waitcnt vmcnt(0)" ::: "memory");  // last tile: drain
        }
        __builtin_amdgcn_s_barrier();          // all waves' tile-t loads visible
        __builtin_amdgcn_sched_barrier(0);     // no ds_read hoists above this point

        const u16* ap = &As[t & 1][0];
        const u16* bp = &Bs[t & 1][0];
        bf16x8 af = *(const bf16x8*)&ap[(wave * 16 + lm) * 32 + quad * 8];
        #pragma unroll
        for (int j = 0; j < 16; ++j) {
            bf16x8 bfr = *(const bf16x8*)&bp[(j * 16 + lm) * 32 + quad * 8];
            acc[j] = __builtin_amdgcn_mfma_f32_16x16x32_bf16(af, bfr, acc[j], 0, 0, 0);
        }

        __builtin_amdgcn_sched_barrier(0);     // no ds_read sinks below (buf reused at t+2)
        __builtin_amdgcn_s_barrier();          // all waves done reading buf before restage
        __builtin_amdgcn_sched_barrier(0);
    }

    // epilogue (v1): per row relu + bias, + residual H, LN over 256 cols, write bf16
    #pragma unroll
    for (int r = 0; r < 4; ++r) {
        int grow = n0 + wave * 16 + quad * 4 + r;   // uniform across the 16 lm lanes
        if (grow >= N) continue;
        float v[16];
        float ps = 0.f, pq = 0.f;
        #pragma unroll
        for (int j = 0; j < 16; ++j) {
            int col = j * 16 + lm;
            float x = fmaxf(acc[j][r] + bias[col], 0.f);
            x += bf2f(H[(size_t)grow * H_DIM + col]);
            v[j] = x; ps += x; pq += x * x;
        }
        #pragma unroll
        for (int off = 1; off < 16; off <<= 1) {
            ps += __shfl_xor(ps, off, 64);
            pq += __shfl_xor(pq, off, 64);
        }
        float mean = ps * (1.0f / H_DIM);
        float var  = pq * (1.0f / H_DIM) - mean * mean;
        float inv  = rsqrtf(var + EPS_LN);
        #pragma unroll
        for (int j = 0; j < 16; ++j) {
            int col = j * 16 + lm;
            H[(size_t)grow * H_DIM + col] = f2bf((v[j] - mean) * inv * lng[col] + lnb[col]);
        }
    }
}

// ---------------- conversions ----------------
__global__ void xconv_kernel(const float* __restrict__ x, u16* __restrict__ o, int n4)
{
    int i = blockIdx.x * blockDim.x + threadIdx.x;
    if (i >= n4) return;
    float4 v = ((const float4*)x)[i];
    ushort4 u;
    u.x = f2bf(v.x); u.y = f2bf(v.y); u.z = f2bf(v.z); u.w = f2bf(v.w);
    ((ushort4*)o)[i] = u;
}

__global__ void wconv_kernel(const float* __restrict__ W, u16* __restrict__ WT,
                             int K, int M, int count)
{
    int idx = blockIdx.x * blockDim.x + threadIdx.x;
    int per = K * M;
    if (idx >= per * count) return;
    int b = idx / per, rem = idx - b * per;
    int k = rem / M, m = rem - k * M;
    WT[(size_t)b * per + (size_t)m * K + k] = f2bf(W[idx]);
}

__global__ void wsum_kernel(const float* __restrict__ Wself, u16* __restrict__ WT)
{
    int idx = blockIdx.x * blockDim.x + threadIdx.x;
    const int per = H_DIM * H_DIM;
    if (idx >= 2 * per) return;
    int l = idx / per, rem = idx - l * per;
    int k = rem / H_DIM, m = rem - k * H_DIM;
    float v = Wself[(size_t)(l * 3 + 0) * per + rem] + Wself[(size_t)(l * 3 + 1) * per + rem];
    WT[(size_t)l * per + (size_t)m * H_DIM + k] = f2bf(v);
}

__global__ void bsum_kernel(const float* __restrict__ bconv, float* __restrict__ bsum)
{
    int idx = blockIdx.x * blockDim.x + threadIdx.x;
    if (idx >= 2 * H_DIM) return;
    int l = idx >> 8, j = idx & 255;
    bsum[idx] = bconv[(l * 3 + 0) * H_DIM + j] + bconv[(l * 3 + 1) * H_DIM + j];
}

// ---------------- CSR build ----------------
__global__ void degi_kernel(const int* __restrict__ dst, int* __restrict__ deg, int E)
{
    int i = blockIdx.x * blockDim.x + threadIdx.x;
    if (i < E) atomicAdd(&deg[dst[i]], 1);
}

__device__ __forceinline__ int block_exscan256(int val, int* lds, int* total)
{
    int t = threadIdx.x;
    lds[t] = val;
    __syncthreads();
    #pragma unroll
    for (int off = 1; off < 256; off <<= 1) {
        int y = (t >= off) ? lds[t - off] : 0;
        __syncthreads();
        lds[t] += y;
        __syncthreads();
    }
    int inc = lds[t];
    *total = lds[255];
    __syncthreads();
    return inc - val;
}

__global__ void scan1_kernel(const int* __restrict__ in, int* __restrict__ out,
                             int* __restrict__ sums, int n)
{
    __shared__ int lds[256];
    int t = threadIdx.x;
    int base = blockIdx.x * 1024 + t * 4;
    int v0 = 0, v1 = 0, v2 = 0, v3 = 0;
    if (base + 3 < n) {
        int4 q = *(const int4*)(in + base);
        v0 = q.x; v1 = q.y; v2 = q.z; v3 = q.w;
    } else {
        if (base     < n) v0 = in[base];
        if (base + 1 < n) v1 = in[base + 1];
        if (base + 2 < n) v2 = in[base + 2];
    }
    int tot = v0 + v1 + v2 + v3, bt;
    int ex = block_exscan256(tot, lds, &bt);
    if (base     < n) out[base]     = ex;
    if (base + 1 < n) out[base + 1] = ex + v0;
    if (base + 2 < n) out[base + 2] = ex + v0 + v1;
    if (base + 3 < n) out[base + 3] = ex + v0 + v1 + v2;
    if (t == 0) sums[blockIdx.x] = bt;
}

__global__ void scan2_kernel(int* __restrict__ sums, int nc)
{
    __shared__ int lds[256];
    int t = threadIdx.x;
    int v = (t < nc) ? sums[t] : 0;
    int bt;
    int ex = block_exscan256(v, lds, &bt);
    if (t < nc) sums[t] = ex;
}

__global__ void scan3_kernel(int* __restrict__ cur, const int* __restrict__ sums, int n)
{
    int i = blockIdx.x * blockDim.x + threadIdx.x;
    if (i < n) cur[i] += sums[i >> 10];
}

__global__ void csr_fill_kernel(const int* __restrict__ src, const int* __restrict__ dst,
                                int* __restrict__ cur, int* __restrict__ csr, int E)
{
    int e = blockIdx.x * blockDim.x + threadIdx.x;
    if (e < E) {
        int pos = atomicAdd(&cur[dst[e]], 1);
        csr[pos] = src[e];
    }
}

// ---------------- pull-style mean aggregation: 2 dst rows per wave, 16 B/lane ----------------
typedef unsigned short u16x8 __attribute__((ext_vector_type(8)));

__launch_bounds__(256)
__global__ void gather_mean_kernel(const u16* __restrict__ h, const int* __restrict__ cur,
                                   const int* __restrict__ deg, const int* __restrict__ csr,
                                   u16* __restrict__ agg, int N)
{
    int gid = blockIdx.x * blockDim.x + threadIdx.x;
    int d = gid >> 5;
    if (d >= N) return;
    int l = gid & 31;               // 32 chunks of 8 bf16 per 256-wide row
    int dg = deg[d];
    int o  = cur[d] - dg;
    float a[8] = {};
    for (int i = 0; i < dg; ++i) {
        int s = csr[o + i];
        u16x8 v = *(const u16x8*)(h + (size_t)s * H_DIM + l * 8);
        #pragma unroll
        for (int t = 0; t < 8; ++t) a[t] += bf2f(v[t]);
    }
    float r = (dg > 0) ? (1.0f / (float)dg) : 0.f;
    u16x8 u;
    #pragma unroll
    for (int t = 0; t < 8; ++t) u[t] = f2bf(a[t] * r);
    *(u16x8*)(agg + (size_t)d * H_DIM + l * 8) = u;
}

// ---------------- in-place log_softmax ----------------
__launch_bounds__(256)
__global__ void logsoftmax_kernel(float* __restrict__ x, int N, int C)
{
    int gid = blockIdx.x * blockDim.x + threadIdx.x;
    int row = gid >> 6;
    if (row >= N) return;
    int lane = threadIdx.x & 63;
    float v = (lane < C) ? x[(size_t)row * C + lane] : -3.0e38f;
    float m = v;
    #pragma unroll
    for (int off = 32; off; off >>= 1) m = fmaxf(m, __shfl_xor(m, off, 64));
    float e = (lane < C) ? __expf(v - m) : 0.f;
    float s = e;
    #pragma unroll
    for (int off = 32; off; off >>= 1) s += __shfl_xor(s, off, 64);
    float ls = logf(s);
    if (lane < C) x[(size_t)row * C + lane] = v - m - ls;
}

// ======================================================================================
extern "C" void kernel_launch(void* const* d_in, const int* in_sizes, int n_in,
                              void* d_out, int out_size, void* d_ws, size_t ws_size,
                              hipStream_t stream)
{
    const float* x_author = (const float*)d_in[0];
    const float* x_paper  = (const float*)d_in[1];
    const int* e0s = (const int*)d_in[2]; const int* e0d = (const int*)d_in[3];
    const int* e1s = (const int*)d_in[4]; const int* e1d = (const int*)d_in[5];
    const int* e2s = (const int*)d_in[6]; const int* e2d = (const int*)d_in[7];
    const float* embWa = (const float*)d_in[8];  const float* embba = (const float*)d_in[9];
    const float* embWp = (const float*)d_in[10]; const float* embbp = (const float*)d_in[11];
    const float* Wself  = (const float*)d_in[12];
    const float* Wneigh = (const float*)d_in[13];
    const float* bconv  = (const float*)d_in[14];
    const float* lnga = (const float*)d_in[15]; const float* lnba = (const float*)d_in[16];
    const float* lngp = (const float*)d_in[17]; const float* lnbp = (const float*)d_in[18];
    const float* pW1a = (const float*)d_in[19]; const float* pb1a = (const float*)d_in[20];
    const float* pW2a = (const float*)d_in[21]; const float* pb2a = (const float*)d_in[22];
    const float* pW1p = (const float*)d_in[23]; const float* pb1p = (const float*)d_in[24];
    const float* pW2p = (const float*)d_in[25];

    // ---- workspace carve ----
    char* wp = (char*)d_ws;
    auto carveF = [&](size_t n) { float* p = (float*)wp; wp += n * sizeof(float); return p; };
    auto carveU = [&](size_t n) { u16* p = (u16*)wp; wp += n * sizeof(u16); return p; };
    auto carveI = [&](size_t n) { int* p = (int*)wp; wp += n * sizeof(int); return p; };

    float* BSUM = carveF(2 * H_DIM);

    u16* HA16  = carveU((size_t)A_N * H_DIM);
    u16* HP16  = carveU((size_t)P_N * H_DIM);
    u16* AGG0  = carveU((size_t)P_N * H_DIM);
    u16* AGG1  = carveU((size_t)P_N * H_DIM);
    u16* AGGA  = carveU((size_t)A_N * H_DIM);
    u16* XA16  = carveU((size_t)A_N * DIN);
    u16* XP16  = carveU((size_t)P_N * DIN);
    u16* WsT    = carveU(6 * H_DIM * H_DIM);
    u16* WnT    = carveU(6 * H_DIM * H_DIM);
    u16* WsumT  = carveU(2 * H_DIM * H_DIM);
    u16* embWaT = carveU(DIN * H_DIM);
    u16* embWpT = carveU(DIN * H_DIM);
    u16* pW1aT  = carveU(H_DIM * H_DIM);
    u16* pW2aT  = carveU(H_DIM * C_CLS);
    u16* pW1pT  = carveU(H_DIM * H_DIM);
    u16* pW2pT  = carveU(H_DIM * H_DIM);

    int* ideg = carveI(2 * P_N + A_N);
    int* icur = carveI(2 * P_N + A_N);
    int* icsr = carveI(3 * E_N);
    int* isum = carveI(3 * 256);

    int* deg0 = ideg; int* deg1 = deg0 + P_N; int* deg2 = deg1 + P_N;
    int* cur0 = icur; int* cur1 = cur0 + P_N; int* cur2 = cur1 + P_N;
    int* csr0 = icsr; int* csr1 = csr0 + E_N; int* csr2 = csr1 + E_N;
    int* sum0 = isum; int* sum1 = sum0 + 256; int* sum2 = sum1 + 256;

    float* oaOut = (float*)d_out;                  // A_N * C_CLS
    float* opOut = oaOut + (size_t)A_N * C_CLS;    // P_N * H_DIM

    auto gemm = [&](const u16* a0, const u16* b0, const u16* a1, const u16* b1,
                    const u16* a2, const u16* b2, int nseg, const float* bias,
                    float* c32, u16* c16, int N, int K, int M, int relu) {
        dim3 grid((M + GBM - 1) / GBM, (N + GBN - 1) / GBN);
        gemm_mfma2<<<grid, 256, 0, stream>>>(a0, a1, a2, b0, b1, b2, nseg, bias, c32, c16, N, K, M, relu);
    };

    // ---- weight / input conversions ----
    xconv_kernel<<<((A_N * DIN / 4) + 255) / 256, 256, 0, stream>>>(x_author, XA16, A_N * DIN / 4);
    xconv_kernel<<<((P_N * DIN / 4) + 255) / 256, 256, 0, stream>>>(x_paper,  XP16, P_N * DIN / 4);
    wconv_kernel<<<(DIN * H_DIM + 255) / 256, 256, 0, stream>>>(embWa, embWaT, DIN, H_DIM, 1);
    wconv_kernel<<<(DIN * H_DIM + 255) / 256, 256, 0, stream>>>(embWp, embWpT, DIN, H_DIM, 1);
    wconv_kernel<<<(6 * H_DIM * H_DIM + 255) / 256, 256, 0, stream>>>(Wself,  WsT, H_DIM, H_DIM, 6);
    wconv_kernel<<<(6 * H_DIM * H_DIM + 255) / 256, 256, 0, stream>>>(Wneigh, WnT, H_DIM, H_DIM, 6);
    wsum_kernel<<<(2 * H_DIM * H_DIM + 255) / 256, 256, 0, stream>>>(Wself, WsumT);
    bsum_kernel<<<2, 256, 0, stream>>>(bconv, BSUM);
    wconv_kernel<<<(H_DIM * H_DIM + 255) / 256, 256, 0, stream>>>(pW1a, pW1aT, H_DIM, H_DIM, 1);
    wconv_kernel<<<(H_DIM * C_CLS + 255) / 256, 256, 0, stream>>>(pW2a, pW2aT, H_DIM, C_CLS, 1);
    wconv_kernel<<<(H_DIM * H_DIM + 255) / 256, 256, 0, stream>>>(pW1p, pW1pT, H_DIM, H_DIM, 1);
    wconv_kernel<<<(H_DIM * H_DIM + 255) / 256, 256, 0, stream>>>(pW2p, pW2pT, H_DIM, H_DIM, 1);

    // ---- CSR build ----
    hipMemsetAsync(ideg, 0, (size_t)(2 * P_N + A_N) * sizeof(int), stream);
    const int eB = (E_N + 255) / 256;
    degi_kernel<<<eB, 256, 0, stream>>>(e0d, deg0, E_N);
    degi_kernel<<<eB, 256, 0, stream>>>(e1d, deg1, E_N);
    degi_kernel<<<eB, 256, 0, stream>>>(e2d, deg2, E_N);

    auto build_scan = [&](int* deg, int* cur, int* sums, int n) {
        int nc = (n + 1023) / 1024;
        scan1_kernel<<<nc, 256, 0, stream>>>(deg, cur, sums, n);
        scan2_kernel<<<1, 256, 0, stream>>>(sums, nc);
        scan3_kernel<<<(n + 255) / 256, 256, 0, stream>>>(cur, sums, n);
    };
    build_scan(deg0, cur0, sum0, P_N);
    build_scan(deg1, cur1, sum1, P_N);
    build_scan(deg2, cur2, sum2, A_N);

    csr_fill_kernel<<<eB, 256, 0, stream>>>(e0s, e0d, cur0, csr0, E_N);
    csr_fill_kernel<<<eB, 256, 0, stream>>>(e1s, e1d, cur1, csr1, E_N);
    csr_fill_kernel<<<eB, 256, 0, stream>>>(e2s, e2d, cur2, csr2, E_N);

    // ---- input embeddings (bf16 out) ----
    gemm(XA16, embWaT, 0, 0, 0, 0, 1, embba, nullptr, HA16, A_N, DIN, H_DIM, 0);
    gemm(XP16, embWpT, 0, 0, 0, 0, 1, embbp, nullptr, HP16, P_N, DIN, H_DIM, 0);

    const int gaBlkP = (P_N * 32 + 255) / 256;
    const int gaBlkA = (A_N * 32 + 255) / 256;
    const size_t W2 = (size_t)H_DIM * H_DIM;

    for (int l = 0; l < 2; ++l) {
        // aggregations (read pre-update H)
        gather_mean_kernel<<<gaBlkP, 256, 0, stream>>>(HA16, cur0, deg0, csr0, AGG0, P_N);
        gather_mean_kernel<<<gaBlkP, 256, 0, stream>>>(HP16, cur1, deg1, csr1, AGG1, P_N);
        gather_mean_kernel<<<gaBlkA, 256, 0, stream>>>(HP16, cur2, deg2, csr2, AGGA, A_N);

        // paper: hp@(Ws0+Ws1) + agg0@Wn0 + agg1@Wn1 + (b0+b1), then relu+residual+LN in-place
        gemm_ln<<<(P_N + 63) / 64, 256, 0, stream>>>(
            HP16, AGG0, AGG1,
            WsumT + (size_t)l * W2, WnT + (size_t)(l * 3 + 0) * W2, WnT + (size_t)(l * 3 + 1) * W2,
            3, BSUM + l * H_DIM, lngp, lnbp, HP16, P_N);

        // author: ha@Ws2 + aggA@Wn2 + b2, then relu+residual+LN in-place
        gemm_ln<<<(A_N + 63) / 64, 256, 0, stream>>>(
            HA16, AGGA, (const u16*)nullptr,
            WsT + (size_t)(l * 3 + 2) * W2, WnT + (size_t)(l * 3 + 2) * W2, (const u16*)nullptr,
            2, bconv + (size_t)(l * 3 + 2) * H_DIM, lnga, lnba, HA16, A_N);
    }

    // ---- output heads ----
    u16* TMPA16 = AGGA;   // free after layers
    u16* TMPP16 = AGG0;
    gemm(HA16, pW1aT, 0, 0, 0, 0, 1, pb1a, nullptr, TMPA16, A_N, H_DIM, H_DIM, 1);
    gemm(TMPA16, pW2aT, 0, 0, 0, 0, 1, pb2a, oaOut, nullptr, A_N, H_DIM, C_CLS, 0);
    logsoftmax_kernel<<<(A_N * 64 + 255) / 256, 256, 0, stream>>>(oaOut, A_N, C_CLS);

    gemm(HP16, pW1pT, 0, 0, 0, 0, 1, pb1p, nullptr, TMPP16, P_N, H_DIM, H_DIM, 1);
    gemm(TMPP16, pW2pT, 0, 0, 0, 0, 1, nullptr, opOut, nullptr, P_N, H_DIM, H_DIM, 0);
}